// Round 1
// baseline (365.765 us; speedup 1.0000x reference)
//
#include <hip/hip_runtime.h>
#include <cstdint>
#include <cstddef>

typedef __attribute__((ext_vector_type(8))) short short8;
typedef __attribute__((ext_vector_type(4))) float f32x4;

#define D_FEAT 512
#define D_HID  1024
#define NCOL   2048   // hidden cols = 2*D_HID (U | V)
#define NCHUNK 32     // 2048/64 scale chunks per row

__device__ __forceinline__ unsigned short f2bf(float f) {
    unsigned u = __builtin_bit_cast(unsigned, f);
    u += 0x7FFFu + ((u >> 16) & 1u);   // round-to-nearest-even
    return (unsigned short)(u >> 16);
}

// compiler-fence + raw barrier: no implicit vmcnt drain (that drain is the 2-phase disease)
#define FENCE() asm volatile("" ::: "memory")
#define BAR()   do { FENCE(); __builtin_amdgcn_s_barrier(); FENCE(); } while (0)

// ---------- kernel 1: x fp32 -> bf16 ----------
__global__ __launch_bounds__(256) void cast_x_kernel(const float* __restrict__ x,
                                                     unsigned short* __restrict__ xb,
                                                     int n) {
    int i = (blockIdx.x * 256 + threadIdx.x) * 8;
    if (i >= n) return;
    const float4* xp = (const float4*)(x + i);
    float4 a = xp[0], b = xp[1];
    short8 o;
    o[0] = (short)f2bf(a.x); o[1] = (short)f2bf(a.y);
    o[2] = (short)f2bf(a.z); o[3] = (short)f2bf(a.w);
    o[4] = (short)f2bf(b.x); o[5] = (short)f2bf(b.y);
    o[6] = (short)f2bf(b.z); o[7] = (short)f2bf(b.w);
    *(short8*)(xb + i) = o;
}

// ---------- kernel 2: W1 [1024][1024] fp32 -> w1t bf16 [2048][512] (B^T, U|V stacked) ----------
__global__ __launch_bounds__(256) void transpose_w1_kernel(const float* __restrict__ W1,
                                                           unsigned short* __restrict__ w1t) {
    __shared__ float tile[32][33];
    const int half = blockIdx.z;
    const int kb = blockIdx.y * 32;
    const int nb = blockIdx.x * 32;
    const int tx = threadIdx.x, ty = threadIdx.y;
    #pragma unroll
    for (int i = 0; i < 32; i += 8)
        tile[ty + i][tx] = W1[(size_t)(half * 512 + kb + ty + i) * 1024 + nb + tx];
    __syncthreads();
    #pragma unroll
    for (int i = 0; i < 32; i += 8)
        w1t[(size_t)(half * 1024 + nb + ty + i) * 512 + kb + tx] = f2bf(tile[tx][ty + i]);
}

// ---------- kernel 3: qUV = quant_u8(xb @ w1t^T + b1) with per-(16row,64col) scales ----------
// 256x256 tile, BK=64, 8 waves (2M x 4N), 512 threads.
// Schedule: 4 phases per K-tile, {ds_read subtile | stage prefetch | s_barrier |
// lgkmcnt(0) | setprio(1) | 16 MFMA | setprio(0) | s_barrier}; one counted vmcnt(0)
// per K-tile placed 2-4 phases AFTER the loads it waits on (raw barriers carry no drain).
// LDS 128 KiB: double-buffered A[256][64] + B[256][64] bf16, per-8x64-slot XOR swizzle
// (pre-swizzled global source + swizzled ds_read — proven conflict-free in prior version).
// Each wave stages exactly the A-half (wr) and B-half (wc>>1) it consumes, so its own
// vmcnt(0) covers its needs; the boundary barrier covers co-stagers.
#define BM 256
#define BN 256
#define BK 64
#define GM 32            // m-blocks per supergroup: GM*NB2 = 256 blocks ~ one residency window
#define NB2 (NCOL / BN)  // 8

__global__ __launch_bounds__(512, 2) void gemm_uv_kernel(
    const unsigned short* __restrict__ xb,
    const unsigned short* __restrict__ w1t,
    const float* __restrict__ b1,
    unsigned char* __restrict__ qUV,      // [M][2048] uint8 (biased +128)
    float* __restrict__ scales,           // [M][32] fp32 (duplicated across 16-row groups)
    int M, int MB)
{
    __shared__ __align__(16) unsigned short smem[65536];   // 128 KiB
    // A0 [0,16384) | A1 [16384,32768) | B0 [32768,49152) | B1 [49152,65536)  (shorts)

    const int bid = blockIdx.x;
    int g    = bid / (GM * NB2);
    int rem  = bid - g * (GM * NB2);
    int base = g * GM;
    int gm   = MB - base; if (gm > GM) gm = GM;
    int mb   = base + rem % gm;
    int nb   = rem / gm;
    const int m0 = mb * BM;
    const int n0 = nb * BN;

    const int tid  = threadIdx.x;
    const int wave = tid >> 6;
    const int lane = tid & 63;
    const int q    = lane >> 4;
    const int l15  = lane & 15;
    const int wr   = wave >> 2;          // 0..1  (M half)
    const int wc   = wave & 3;           // 0..3  (N quarter)
    const int bh   = wc >> 1;            // B half this wave consumes

    const int ar    = lane >> 3;                 // staging row within slot
    const int swcol = ((lane & 7) ^ ar) * 8;     // pre-swizzled global col-group
    const int swz   = l15 & 7;                   // read-side swizzle key

    // staged slot assignment: wave stages its own A-half / B-half share
    const int slotA0 = wr * 16 + wc * 4;
    const int slotB0 = bh * 16 + (wr * 2 + (wc & 1)) * 4;
    int rowA[4], rowB[4];
    #pragma unroll
    for (int j = 0; j < 4; ++j) {
        int m = m0 + (slotA0 + j) * 8 + ar;
        rowA[j] = (m < M) ? m : (M - 1);
        rowB[j] = n0 + (slotB0 + j) * 8 + ar;
    }

    unsigned short* const sAbuf[2] = { smem,         smem + 16384 };
    unsigned short* const sBbuf[2] = { smem + 32768, smem + 49152 };

    auto stageA = [&](int t, int cb) {
        const int k0 = t * BK;
        #pragma unroll
        for (int j = 0; j < 4; ++j)
            __builtin_amdgcn_global_load_lds(
                (const __attribute__((address_space(1))) void*)(xb + ((size_t)rowA[j] << 9) + k0 + swcol),
                (__attribute__((address_space(3))) void*)(sAbuf[cb] + (slotA0 + j) * 512),
                16, 0, 0);
    };
    auto stageB = [&](int t, int cb) {
        const int k0 = t * BK;
        #pragma unroll
        for (int j = 0; j < 4; ++j)
            __builtin_amdgcn_global_load_lds(
                (const __attribute__((address_space(1))) void*)(w1t + ((size_t)rowB[j] << 9) + k0 + swcol),
                (__attribute__((address_space(3))) void*)(sBbuf[cb] + (slotB0 + j) * 512),
                16, 0, 0);
    };
    auto readA = [&](int cb, int mt, int ks) -> short8 {
        int row = wr * 128 + mt * 16 + l15;
        return *(const short8*)(sAbuf[cb] + row * 64 + (((q | (ks << 2)) ^ swz) * 8));
    };
    auto readB = [&](int cb, int nt, int ks) -> short8 {
        int row = wc * 64 + nt * 16 + l15;
        return *(const short8*)(sBbuf[cb] + row * 64 + (((q | (ks << 2)) ^ swz) * 8));
    };

    // bias pre-load: acc seeded with b1 so the epilogue never adds it
    float b1v[4];
    #pragma unroll
    for (int nt = 0; nt < 4; ++nt) {
        int n = n0 + wc * 64 + nt * 16 + l15;
        b1v[nt] = (n < D_HID) ? b1[n] : 0.f;
    }
    f32x4 acc[8][4];
    #pragma unroll
    for (int i = 0; i < 8; ++i)
        #pragma unroll
        for (int j = 0; j < 4; ++j)
            acc[i][j] = (f32x4){b1v[j], b1v[j], b1v[j], b1v[j]};

    // prologue: stage K-tile 0 into buf0, drain once, sync
    stageA(0, 0);
    stageB(0, 0);
    asm volatile("s_waitcnt vmcnt(0)" ::: "memory");
    BAR();

    #pragma unroll
    for (int t = 0; t < 8; ++t) {
        const int c = t & 1;
        short8 a[4], bk0[4], bk1[4];

        // ---- phase 0: B(ks=0) + A(mt 0..3, ks=0); stage next A-half ----
        #pragma unroll
        for (int nt = 0; nt < 4; ++nt) bk0[nt] = readB(c, nt, 0);
        #pragma unroll
        for (int i = 0; i < 4; ++i)    a[i]    = readA(c, i, 0);
        if (t < 7) stageA(t + 1, c ^ 1);
        BAR();
        asm volatile("s_waitcnt lgkmcnt(0)" ::: "memory");
        __builtin_amdgcn_s_setprio(1);
        #pragma unroll
        for (int mt = 0; mt < 4; ++mt)
            #pragma unroll
            for (int nt = 0; nt < 4; ++nt)
                acc[mt][nt] = __builtin_amdgcn_mfma_f32_16x16x32_bf16(a[mt], bk0[nt], acc[mt][nt], 0, 0, 0);
        __builtin_amdgcn_s_setprio(0);
        BAR();

        // ---- phase 1: B(ks=1) + A(mt 0..3, ks=1); stage next B-half ----
        #pragma unroll
        for (int nt = 0; nt < 4; ++nt) bk1[nt] = readB(c, nt, 1);
        #pragma unroll
        for (int i = 0; i < 4; ++i)    a[i]    = readA(c, i, 1);
        if (t < 7) stageB(t + 1, c ^ 1);
        BAR();
        asm volatile("s_waitcnt lgkmcnt(0)" ::: "memory");
        __builtin_amdgcn_s_setprio(1);
        #pragma unroll
        for (int mt = 0; mt < 4; ++mt)
            #pragma unroll
            for (int nt = 0; nt < 4; ++nt)
                acc[mt][nt] = __builtin_amdgcn_mfma_f32_16x16x32_bf16(a[mt], bk1[nt], acc[mt][nt], 0, 0, 0);
        __builtin_amdgcn_s_setprio(0);
        BAR();

        // ---- phase 2: A(mt 4..7, ks=0), reuse bk0 ----
        #pragma unroll
        for (int i = 0; i < 4; ++i) a[i] = readA(c, 4 + i, 0);
        BAR();
        asm volatile("s_waitcnt lgkmcnt(0)" ::: "memory");
        __builtin_amdgcn_s_setprio(1);
        #pragma unroll
        for (int mt = 0; mt < 4; ++mt)
            #pragma unroll
            for (int nt = 0; nt < 4; ++nt)
                acc[4 + mt][nt] = __builtin_amdgcn_mfma_f32_16x16x32_bf16(a[mt], bk0[nt], acc[4 + mt][nt], 0, 0, 0);
        __builtin_amdgcn_s_setprio(0);
        BAR();

        // ---- phase 3: A(mt 4..7, ks=1), reuse bk1; K-tile boundary vmcnt ----
        #pragma unroll
        for (int i = 0; i < 4; ++i) a[i] = readA(c, 4 + i, 1);
        BAR();
        asm volatile("s_waitcnt lgkmcnt(0)" ::: "memory");
        __builtin_amdgcn_s_setprio(1);
        #pragma unroll
        for (int mt = 0; mt < 4; ++mt)
            #pragma unroll
            for (int nt = 0; nt < 4; ++nt)
                acc[4 + mt][nt] = __builtin_amdgcn_mfma_f32_16x16x32_bf16(a[mt], bk1[nt], acc[4 + mt][nt], 0, 0, 0);
        __builtin_amdgcn_s_setprio(0);
        // next K-tile's loads were issued 2-4 phases ago -> this wait is ~free
        if (t < 7) asm volatile("s_waitcnt vmcnt(0)" ::: "memory");
        BAR();
    }

    // ---- epilogue: per-(16-row,64-col) absmax, magic-fmaf uint8 quantize ----
    float msc[8], minv[8];
    #pragma unroll
    for (int mt = 0; mt < 8; ++mt) {
        float m_ = 1e-30f;
        #pragma unroll
        for (int nt = 0; nt < 4; ++nt)
            #pragma unroll
            for (int r = 0; r < 4; ++r)
                m_ = fmaxf(m_, fabsf(acc[mt][nt][r]));
        #pragma unroll
        for (int off = 1; off < 64; off <<= 1)
            m_ = fmaxf(m_, __shfl_xor(m_, off));
        msc[mt]  = m_ * (1.0f / 127.0f);
        minv[mt] = 127.0f * __builtin_amdgcn_rcpf(m_);
    }

    // all K-loop LDS reads retired (data-dep waited before final MFMAs + final barrier)
    unsigned char* ep8 = (unsigned char*)smem + wave * 8192;   // wave-private [128][64] u8
    const float MAGIC = 12583040.0f;   // 1.5*2^23 + 128: low byte = rint(x)+128
    #pragma unroll
    for (int mt = 0; mt < 8; ++mt)
        #pragma unroll
        for (int nt = 0; nt < 4; ++nt)
            #pragma unroll
            for (int r = 0; r < 4; ++r) {
                float f = fmaf(acc[mt][nt][r], minv[mt], MAGIC);
                // nt^q col swizzle: breaks the 4-q-group same-bank collision (16-way -> 4-way)
                ep8[(mt * 16 + q * 4 + r) * 64 + ((nt ^ q) * 16) + l15] =
                    (unsigned char)__builtin_bit_cast(unsigned, f);
            }
    const int chunk = (n0 + wc * 64) >> 6;
    #pragma unroll
    for (int h = 0; h < 2; ++h) {
        int srow = m0 + wr * 128 + h * 64 + q * 16 + l15;
        if (srow < M) scales[(size_t)srow * NCHUNK + chunk] = msc[h * 4 + q];
    }
    // same-wave LDS write->read: wave-private region, no barrier needed
    #pragma unroll
    for (int it = 0; it < 8; ++it) {
        int flat = it * 64 + lane;          // 0..511
        int r   = flat >> 2;                // row 0..127
        int cI  = flat & 3;                 // 16B col group
        int m   = m0 + wr * 128 + r;
        if (m < M) {
            int4 v = *(const int4*)(ep8 + r * 64 + ((cI ^ ((r >> 2) & 3)) * 16));
            *(int4*)(qUV + (size_t)m * NCOL + n0 + wc * 64 + cI * 16) = v;
        }
    }
}

// ---------- kernel 4: per-edge score = relu(sU*(qU-128) + sV*(qV-128)) . W2 + b2 ----------
__global__ __launch_bounds__(256) void edge_score_kernel(
    const unsigned char* __restrict__ qUV,
    const float* __restrict__ scales,
    const int* __restrict__ src, const int* __restrict__ dst,
    const float* __restrict__ W2, const float* __restrict__ b2,
    float* __restrict__ out, int E)
{
    const int wave = threadIdx.x >> 6;
    const int lane = threadIdx.x & 63;
    const int gw = blockIdx.x * 4 + wave;
    const int e0 = gw * 2;
    const int e1 = e0 + 1;
    if (e0 >= E) return;
    const bool has1 = (e1 < E);

    const int s0 = src[e0];
    const int d0 = dst[e0];
    const int s1 = has1 ? src[e1] : s0;
    const int d1 = has1 ? dst[e1] : d0;

    uint4 qu0 = *(const uint4*)(qUV + (size_t)s0 * NCOL + lane * 16);
    uint4 qv0 = *(const uint4*)(qUV + (size_t)d0 * NCOL + D_HID + lane * 16);
    uint4 qu1 = *(const uint4*)(qUV + (size_t)s1 * NCOL + lane * 16);
    uint4 qv1 = *(const uint4*)(qUV + (size_t)d1 * NCOL + D_HID + lane * 16);
    const int ch = lane >> 2;
    float su0 = scales[(size_t)s0 * NCHUNK + ch];
    float sv0 = scales[(size_t)d0 * NCHUNK + 16 + ch];
    float su1 = scales[(size_t)s1 * NCHUNK + ch];
    float sv1 = scales[(size_t)d1 * NCHUNK + 16 + ch];
    // h = su*(ub-128) + sv*(vb-128) = fmaf(ub,su, fmaf(vb,sv, cc)), cc = -128*(su+sv)
    float cc0 = -128.0f * (su0 + sv0);
    float cc1 = -128.0f * (su1 + sv1);

    const float4* wp = (const float4*)(W2 + lane * 16);
    float4 wa = wp[0], wb = wp[1], wc = wp[2], wd = wp[3];
    float w[16] = {wa.x, wa.y, wa.z, wa.w, wb.x, wb.y, wb.z, wb.w,
                   wc.x, wc.y, wc.z, wc.w, wd.x, wd.y, wd.z, wd.w};
    const float bias = b2[0];

    const unsigned* u0w = (const unsigned*)&qu0; const unsigned* v0w = (const unsigned*)&qv0;
    const unsigned* u1w = (const unsigned*)&qu1; const unsigned* v1w = (const unsigned*)&qv1;

    float acc0 = 0.f, acc1 = 0.f;
    #pragma unroll
    for (int dw = 0; dw < 4; ++dw) {
        #pragma unroll
        for (int b = 0; b < 4; ++b) {
            int k = dw * 4 + b;
            // (float)((w>>8b)&0xFF) -> v_cvt_f32_ubyte[b]
            float ub0 = (float)((u0w[dw] >> (8 * b)) & 0xFFu);
            float vb0 = (float)((v0w[dw] >> (8 * b)) & 0xFFu);
            float h0 = fmaf(ub0, su0, fmaf(vb0, sv0, cc0));
            acc0 = fmaf(fmaxf(h0, 0.f), w[k], acc0);
            float ub1 = (float)((u1w[dw] >> (8 * b)) & 0xFFu);
            float vb1 = (float)((v1w[dw] >> (8 * b)) & 0xFFu);
            float h1 = fmaf(ub1, su1, fmaf(vb1, sv1, cc1));
            acc1 = fmaf(fmaxf(h1, 0.f), w[k], acc1);
        }
    }
    #pragma unroll
    for (int off = 1; off < 64; off <<= 1) {
        acc0 += __shfl_xor(acc0, off);
        acc1 += __shfl_xor(acc1, off);
    }
    if (lane == 0) out[e0] = acc0 + bias;
    if (lane == 1 && has1) out[e1] = acc1 + bias;
}

extern "C" void kernel_launch(void* const* d_in, const int* in_sizes, int n_in,
                              void* d_out, int out_size, void* d_ws, size_t ws_size,
                              hipStream_t stream) {
    const float* x   = (const float*)d_in[0];
    const int*   src = (const int*)d_in[1];
    const int*   dst = (const int*)d_in[2];
    const float* W1  = (const float*)d_in[3];
    const float* b1  = (const float*)d_in[4];
    const float* W2  = (const float*)d_in[5];
    const float* b2  = (const float*)d_in[6];
    float* out = (float*)d_out;

    const int M = in_sizes[0] / D_FEAT;   // 50000 nodes
    const int E = in_sizes[1];            // 200000 edges

    // workspace: qUV u8 [M][2048] | scales f32 [M][32] | xb bf16 [M][512] | w1t bf16 [2048][512]
    char* ws = (char*)d_ws;
    unsigned char*  qUV    = (unsigned char*)ws;
    float*          scales = (float*)(ws + (size_t)M * NCOL);
    unsigned short* xb     = (unsigned short*)(ws + (size_t)M * NCOL + (size_t)M * NCHUNK * 4);
    unsigned short* w1t    = (unsigned short*)(ws + (size_t)M * NCOL + (size_t)M * NCHUNK * 4
                                                  + (size_t)M * D_FEAT * 2);

    const int nx = M * D_FEAT;
    cast_x_kernel<<<(nx / 8 + 255) / 256, 256, 0, stream>>>(x, xb, nx);
    transpose_w1_kernel<<<dim3(32, 16, 2), dim3(32, 8), 0, stream>>>(W1, w1t);
    const int MB = (M + BM - 1) / BM;
    gemm_uv_kernel<<<MB * NB2, 512, 0, stream>>>(xb, w1t, b1, qUV, scales, M, MB);
    edge_score_kernel<<<(E + 7) / 8, 256, 0, stream>>>(qUV, scales, src, dst, W2, b2, out, E);
}

// Round 2
// 363.088 us; speedup vs baseline: 1.0074x; 1.0074x over previous
//
#include <hip/hip_runtime.h>
#include <cstdint>
#include <cstddef>

typedef __attribute__((ext_vector_type(8))) short short8;
typedef __attribute__((ext_vector_type(4))) float f32x4;

#define D_FEAT 512
#define D_HID  1024
#define NCOL   2048   // hidden cols = 2*D_HID (U | V)
#define NCHUNK 32     // 2048/64 scale chunks per row

__device__ __forceinline__ unsigned short f2bf(float f) {
    unsigned u = __builtin_bit_cast(unsigned, f);
    u += 0x7FFFu + ((u >> 16) & 1u);   // round-to-nearest-even
    return (unsigned short)(u >> 16);
}

// compiler-fence + raw barrier: no implicit vmcnt drain
#define FENCE() asm volatile("" ::: "memory")
#define BAR()   do { FENCE(); __builtin_amdgcn_s_barrier(); FENCE(); } while (0)

// ---------- kernel 1: x fp32 -> bf16 ----------
__global__ __launch_bounds__(256) void cast_x_kernel(const float* __restrict__ x,
                                                     unsigned short* __restrict__ xb,
                                                     int n) {
    int i = (blockIdx.x * 256 + threadIdx.x) * 8;
    if (i >= n) return;
    const float4* xp = (const float4*)(x + i);
    float4 a = xp[0], b = xp[1];
    short8 o;
    o[0] = (short)f2bf(a.x); o[1] = (short)f2bf(a.y);
    o[2] = (short)f2bf(a.z); o[3] = (short)f2bf(a.w);
    o[4] = (short)f2bf(b.x); o[5] = (short)f2bf(b.y);
    o[6] = (short)f2bf(b.z); o[7] = (short)f2bf(b.w);
    *(short8*)(xb + i) = o;
}

// ---------- kernel 2: W1 [1024][1024] fp32 -> w1t bf16 [2048][512] (B^T, U|V stacked) ----------
__global__ __launch_bounds__(256) void transpose_w1_kernel(const float* __restrict__ W1,
                                                           unsigned short* __restrict__ w1t) {
    __shared__ float tile[32][33];
    const int half = blockIdx.z;
    const int kb = blockIdx.y * 32;
    const int nb = blockIdx.x * 32;
    const int tx = threadIdx.x, ty = threadIdx.y;
    #pragma unroll
    for (int i = 0; i < 32; i += 8)
        tile[ty + i][tx] = W1[(size_t)(half * 512 + kb + ty + i) * 1024 + nb + tx];
    __syncthreads();
    #pragma unroll
    for (int i = 0; i < 32; i += 8)
        w1t[(size_t)(half * 1024 + nb + ty + i) * 512 + kb + tx] = f2bf(tile[tx][ty + i]);
}

// ---------- kernel 3: qUV = quant_u8(xb @ w1t^T + b1) with per-(16row,64col) scales ----------
// 256x256 tile, BK=64, 8 waves (2M x 4N), 512 threads, 128 KiB dbuf LDS.
// COUNTED-vmcnt schedule (T3+T4): per-wave uniform issue stream, 2 gload_lds/phase:
//   ph0: A34(t+1)->c^1 | ph1: B12(t+1)->c^1 | ph2: B34(t+1)->c^1 | ph3: A12(t+2)->c
// A12(t+2) overwrites buf c's A region (fully consumed by ph2 -> fragments held in regs),
// giving the HBM-latency A stream 3-7 phases of cover; L2-resident B gets 2-3 phases.
// vmcnt(4) at ph0/ph3 only (never 0 in steady state); tail tiles tighten to 2/0.
// Readiness proof: each ds_read is covered by a vmcnt+barrier >=2 phases after its
// staging loads were issued; each stage targets a region whose last reads fed an MFMA
// before the preceding barrier (MFMA data-dep forces ds_read completion).
#define BM 256
#define BN 256
#define BK 64
#define GM 32            // m-blocks per supergroup
#define NB2 (NCOL / BN)  // 8

__global__ __launch_bounds__(512, 2) void gemm_uv_kernel(
    const unsigned short* __restrict__ xb,
    const unsigned short* __restrict__ w1t,
    const float* __restrict__ b1,
    unsigned char* __restrict__ qUV,      // [M][2048] uint8 (biased +128)
    float* __restrict__ scales,           // [M][32] fp32 (duplicated across 16-row groups)
    int M, int MB)
{
    __shared__ __align__(16) unsigned short smem[65536];   // 128 KiB
    // A0 [0,16384) | A1 [16384,32768) | B0 [32768,49152) | B1 [49152,65536)  (shorts)

    const int bid = blockIdx.x;
    int g    = bid / (GM * NB2);
    int rem  = bid - g * (GM * NB2);
    int base = g * GM;
    int gm   = MB - base; if (gm > GM) gm = GM;
    int mb   = base + rem % gm;
    int nb   = rem / gm;
    const int m0 = mb * BM;
    const int n0 = nb * BN;

    const int tid  = threadIdx.x;
    const int wave = tid >> 6;
    const int lane = tid & 63;
    const int q    = lane >> 4;
    const int l15  = lane & 15;
    const int wr   = wave >> 2;          // 0..1  (M half)
    const int wc   = wave & 3;           // 0..3  (N quarter)

    const int ar    = lane >> 3;                 // staging row within slot
    const int swcol = ((lane & 7) ^ ar) * 8;     // pre-swizzled global col-group
    const int swz   = l15 & 7;                   // read-side swizzle key

    // A slots: wave stages slots slotA0..+3 (within the A-half it reads).
    // B slots: interleaved so that BOTH waves' "B12" pair covers rows wc*64+0..31
    // (read at ph0) and "B34" covers rows wc*64+32..63 (read at ph1).
    const int slotA0 = wr * 16 + wc * 4;
    int bslot[4];
    bslot[0] = wc * 8 + wr * 2;     bslot[1] = bslot[0] + 1;
    bslot[2] = wc * 8 + 4 + wr * 2; bslot[3] = bslot[2] + 1;

    int rowA[4], rowB[4];
    #pragma unroll
    for (int j = 0; j < 4; ++j) {
        int m = m0 + (slotA0 + j) * 8 + ar;
        rowA[j] = (m < M) ? m : (M - 1);
        rowB[j] = n0 + bslot[j] * 8 + ar;
    }

    unsigned short* const sAbuf[2] = { smem,         smem + 16384 };
    unsigned short* const sBbuf[2] = { smem + 32768, smem + 49152 };

    auto stageA2 = [&](int t, int cb, int j0) {
        const int k0 = t * BK;
        #pragma unroll
        for (int j = 0; j < 2; ++j)
            __builtin_amdgcn_global_load_lds(
                (const __attribute__((address_space(1))) void*)(xb + ((size_t)rowA[j0 + j] << 9) + k0 + swcol),
                (__attribute__((address_space(3))) void*)(sAbuf[cb] + (slotA0 + j0 + j) * 512),
                16, 0, 0);
    };
    auto stageB2 = [&](int t, int cb, int j0) {
        const int k0 = t * BK;
        #pragma unroll
        for (int j = 0; j < 2; ++j)
            __builtin_amdgcn_global_load_lds(
                (const __attribute__((address_space(1))) void*)(w1t + ((size_t)rowB[j0 + j] << 9) + k0 + swcol),
                (__attribute__((address_space(3))) void*)(sBbuf[cb] + bslot[j0 + j] * 512),
                16, 0, 0);
    };
    auto readA = [&](int cb, int mt, int ks) -> short8 {
        int row = wr * 128 + mt * 16 + l15;
        return *(const short8*)(sAbuf[cb] + row * 64 + (((q | (ks << 2)) ^ swz) * 8));
    };
    auto readB = [&](int cb, int nt, int ks) -> short8 {
        int row = wc * 64 + nt * 16 + l15;
        return *(const short8*)(sBbuf[cb] + row * 64 + (((q | (ks << 2)) ^ swz) * 8));
    };

    // bias pre-load: acc is seeded with b1 so the epilogue never adds it
    float b1v[4];
    #pragma unroll
    for (int nt = 0; nt < 4; ++nt) {
        int n = n0 + wc * 64 + nt * 16 + l15;
        b1v[nt] = (n < D_HID) ? b1[n] : 0.f;
    }
    f32x4 acc[8][4];
    #pragma unroll
    for (int i = 0; i < 8; ++i)
        #pragma unroll
        for (int j = 0; j < 4; ++j)
            acc[i][j] = (f32x4){b1v[j], b1v[j], b1v[j], b1v[j]};

    // prologue — order matches the steady-state per-wave issue stream:
    // A12(0)[(-2,ph3)], A34(0)[(-1,ph0)], B12(0)[(-1,ph1)], B34(0)[(-1,ph2)], A12(1)[(-1,ph3)]
    stageA2(0, 0, 0);
    stageA2(0, 0, 2);
    stageB2(0, 0, 0);
    stageB2(0, 0, 2);
    stageA2(1, 1, 0);
    asm volatile("s_waitcnt vmcnt(4)" ::: "memory");   // certifies A(0), B12(0)
    BAR();

    short8 aR[4][2], bA[2][2], bB[2][2];

    #pragma unroll
    for (int t = 0; t < 8; ++t) {
        const int c = t & 1;

        // ---- phase 0: Q00 = (mt0-3) x (nt0-1); stage A34(t+1) -> c^1 ----
        #pragma unroll
        for (int mt = 0; mt < 4; ++mt)
            #pragma unroll
            for (int ks = 0; ks < 2; ++ks)
                aR[mt][ks] = readA(c, mt, ks);
        #pragma unroll
        for (int nt = 0; nt < 2; ++nt)
            #pragma unroll
            for (int ks = 0; ks < 2; ++ks)
                bA[nt][ks] = readB(c, nt, ks);
        if (t < 7) stageA2(t + 1, c ^ 1, 2);
        BAR();
        __builtin_amdgcn_s_setprio(1);
        #pragma unroll
        for (int ks = 0; ks < 2; ++ks)
            #pragma unroll
            for (int mt = 0; mt < 4; ++mt)
                #pragma unroll
                for (int nt = 0; nt < 2; ++nt)
                    acc[mt][nt] = __builtin_amdgcn_mfma_f32_16x16x32_bf16(aR[mt][ks], bA[nt][ks], acc[mt][nt], 0, 0, 0);
        __builtin_amdgcn_s_setprio(0);
        if (t < 7) { asm volatile("s_waitcnt vmcnt(4)" ::: "memory"); }  // certifies B34(t)
        else       { asm volatile("s_waitcnt vmcnt(0)" ::: "memory"); }  // tail drain
        BAR();

        // ---- phase 1: Q01 = (mt0-3) x (nt2-3); stage B12(t+1) -> c^1 ----
        #pragma unroll
        for (int nt = 0; nt < 2; ++nt)
            #pragma unroll
            for (int ks = 0; ks < 2; ++ks)
                bB[nt][ks] = readB(c, 2 + nt, ks);
        if (t < 7) stageB2(t + 1, c ^ 1, 0);
        BAR();
        __builtin_amdgcn_s_setprio(1);
        #pragma unroll
        for (int ks = 0; ks < 2; ++ks)
            #pragma unroll
            for (int mt = 0; mt < 4; ++mt)
                #pragma unroll
                for (int nt = 0; nt < 2; ++nt)
                    acc[mt][2 + nt] = __builtin_amdgcn_mfma_f32_16x16x32_bf16(aR[mt][ks], bB[nt][ks], acc[mt][2 + nt], 0, 0, 0);
        __builtin_amdgcn_s_setprio(0);
        BAR();

        // ---- phase 2: Q10 = (mt4-7) x (nt0-1); stage B34(t+1) -> c^1 ----
        #pragma unroll
        for (int mt = 0; mt < 4; ++mt)
            #pragma unroll
            for (int ks = 0; ks < 2; ++ks)
                aR[mt][ks] = readA(c, 4 + mt, ks);
        if (t < 7) stageB2(t + 1, c ^ 1, 2);
        BAR();
        __builtin_amdgcn_s_setprio(1);
        #pragma unroll
        for (int ks = 0; ks < 2; ++ks)
            #pragma unroll
            for (int mt = 0; mt < 4; ++mt)
                #pragma unroll
                for (int nt = 0; nt < 2; ++nt)
                    acc[4 + mt][nt] = __builtin_amdgcn_mfma_f32_16x16x32_bf16(aR[mt][ks], bA[nt][ks], acc[4 + mt][nt], 0, 0, 0);
        __builtin_amdgcn_s_setprio(0);
        BAR();

        // ---- phase 3: Q11 = (mt4-7) x (nt2-3); stage A12(t+2) -> buf c (A region free) ----
        if (t < 6) stageA2(t + 2, c, 0);
        BAR();
        __builtin_amdgcn_s_setprio(1);
        #pragma unroll
        for (int ks = 0; ks < 2; ++ks)
            #pragma unroll
            for (int mt = 0; mt < 4; ++mt)
                #pragma unroll
                for (int nt = 0; nt < 2; ++nt)
                    acc[4 + mt][2 + nt] = __builtin_amdgcn_mfma_f32_16x16x32_bf16(aR[mt][ks], bB[nt][ks], acc[4 + mt][2 + nt], 0, 0, 0);
        __builtin_amdgcn_s_setprio(0);
        if (t < 6)      { asm volatile("s_waitcnt vmcnt(4)" ::: "memory"); }  // certifies A(t+1), B12(t+1)
        else if (t == 6){ asm volatile("s_waitcnt vmcnt(2)" ::: "memory"); }  // A12(8) skipped -> tighten
        BAR();
    }

    // ---- epilogue: per-(16-row,64-col) absmax, magic-fmaf uint8 quantize ----
    float msc[8], minv[8];
    #pragma unroll
    for (int mt = 0; mt < 8; ++mt) {
        float m_ = 1e-30f;
        #pragma unroll
        for (int nt = 0; nt < 4; ++nt)
            #pragma unroll
            for (int r = 0; r < 4; ++r)
                m_ = fmaxf(m_, fabsf(acc[mt][nt][r]));
        #pragma unroll
        for (int off = 1; off < 64; off <<= 1)
            m_ = fmaxf(m_, __shfl_xor(m_, off));
        msc[mt]  = m_ * (1.0f / 127.0f);
        minv[mt] = 127.0f * __builtin_amdgcn_rcpf(m_);
    }

    unsigned char* ep8 = (unsigned char*)smem + wave * 8192;   // wave-private [128][64] u8
    const float MAGIC = 12583040.0f;   // 1.5*2^23 + 128: low byte = rint(x)+128
    #pragma unroll
    for (int mt = 0; mt < 8; ++mt)
        #pragma unroll
        for (int nt = 0; nt < 4; ++nt)
            #pragma unroll
            for (int r = 0; r < 4; ++r) {
                float f = fmaf(acc[mt][nt][r], minv[mt], MAGIC);
                // nt^q col swizzle: 16-way -> 4-way byte-write collision
                ep8[(mt * 16 + q * 4 + r) * 64 + ((nt ^ q) * 16) + l15] =
                    (unsigned char)__builtin_bit_cast(unsigned, f);
            }
    const int chunk = (n0 + wc * 64) >> 6;
    #pragma unroll
    for (int h = 0; h < 2; ++h) {
        int srow = m0 + wr * 128 + h * 64 + q * 16 + l15;
        if (srow < M) scales[(size_t)srow * NCHUNK + chunk] = msc[h * 4 + q];
    }
    // same-wave LDS write->read: wave-private region, no barrier needed
    #pragma unroll
    for (int it = 0; it < 8; ++it) {
        int flat = it * 64 + lane;          // 0..511
        int r   = flat >> 2;                // row 0..127
        int cI  = flat & 3;                 // 16B col group
        int m   = m0 + wr * 128 + r;
        if (m < M) {
            int4 v = *(const int4*)(ep8 + r * 64 + ((cI ^ ((r >> 2) & 3)) * 16));
            *(int4*)(qUV + (size_t)m * NCOL + n0 + wc * 64 + cI * 16) = v;
        }
    }
}

// ---------- kernel 4: per-edge score = relu(sU*(qU-128) + sV*(qV-128)) . W2 + b2 ----------
__global__ __launch_bounds__(256) void edge_score_kernel(
    const unsigned char* __restrict__ qUV,
    const float* __restrict__ scales,
    const int* __restrict__ src, const int* __restrict__ dst,
    const float* __restrict__ W2, const float* __restrict__ b2,
    float* __restrict__ out, int E)
{
    const int wave = threadIdx.x >> 6;
    const int lane = threadIdx.x & 63;
    const int gw = blockIdx.x * 4 + wave;
    const int e0 = gw * 2;
    const int e1 = e0 + 1;
    if (e0 >= E) return;
    const bool has1 = (e1 < E);

    const int s0 = src[e0];
    const int d0 = dst[e0];
    const int s1 = has1 ? src[e1] : s0;
    const int d1 = has1 ? dst[e1] : d0;

    uint4 qu0 = *(const uint4*)(qUV + (size_t)s0 * NCOL + lane * 16);
    uint4 qv0 = *(const uint4*)(qUV + (size_t)d0 * NCOL + D_HID + lane * 16);
    uint4 qu1 = *(const uint4*)(qUV + (size_t)s1 * NCOL + lane * 16);
    uint4 qv1 = *(const uint4*)(qUV + (size_t)d1 * NCOL + D_HID + lane * 16);
    const int ch = lane >> 2;
    float su0 = scales[(size_t)s0 * NCHUNK + ch];
    float sv0 = scales[(size_t)d0 * NCHUNK + 16 + ch];
    float su1 = scales[(size_t)s1 * NCHUNK + ch];
    float sv1 = scales[(size_t)d1 * NCHUNK + 16 + ch];
    // h = su*(ub-128) + sv*(vb-128) = fmaf(ub,su, fmaf(vb,sv, cc)), cc = -128*(su+sv)
    float cc0 = -128.0f * (su0 + sv0);
    float cc1 = -128.0f * (su1 + sv1);

    const float4* wp = (const float4*)(W2 + lane * 16);
    float4 wa = wp[0], wb = wp[1], wc = wp[2], wd = wp[3];
    float w[16] = {wa.x, wa.y, wa.z, wa.w, wb.x, wb.y, wb.z, wb.w,
                   wc.x, wc.y, wc.z, wc.w, wd.x, wd.y, wd.z, wd.w};
    const float bias = b2[0];

    const unsigned* u0w = (const unsigned*)&qu0; const unsigned* v0w = (const unsigned*)&qv0;
    const unsigned* u1w = (const unsigned*)&qu1; const unsigned* v1w = (const unsigned*)&qv1;

    float acc0 = 0.f, acc1 = 0.f;
    #pragma unroll
    for (int dw = 0; dw < 4; ++dw) {
        #pragma unroll
        for (int b = 0; b < 4; ++b) {
            int k = dw * 4 + b;
            float ub0 = (float)((u0w[dw] >> (8 * b)) & 0xFFu);
            float vb0 = (float)((v0w[dw] >> (8 * b)) & 0xFFu);
            float h0 = fmaf(ub0, su0, fmaf(vb0, sv0, cc0));
            acc0 = fmaf(fmaxf(h0, 0.f), w[k], acc0);
            float ub1 = (float)((u1w[dw] >> (8 * b)) & 0xFFu);
            float vb1 = (float)((v1w[dw] >> (8 * b)) & 0xFFu);
            float h1 = fmaf(ub1, su1, fmaf(vb1, sv1, cc1));
            acc1 = fmaf(fmaxf(h1, 0.f), w[k], acc1);
        }
    }
    #pragma unroll
    for (int off = 1; off < 64; off <<= 1) {
        acc0 += __shfl_xor(acc0, off);
        acc1 += __shfl_xor(acc1, off);
    }
    if (lane == 0) out[e0] = acc0 + bias;
    if (lane == 1 && has1) out[e1] = acc1 + bias;
}

extern "C" void kernel_launch(void* const* d_in, const int* in_sizes, int n_in,
                              void* d_out, int out_size, void* d_ws, size_t ws_size,
                              hipStream_t stream) {
    const float* x   = (const float*)d_in[0];
    const int*   src = (const int*)d_in[1];
    const int*   dst = (const int*)d_in[2];
    const float* W1  = (const float*)d_in[3];
    const float* b1  = (const float*)d_in[4];
    const float* W2  = (const float*)d_in[5];
    const float* b2  = (const float*)d_in[6];
    float* out = (float*)d_out;

    const int M = in_sizes[0] / D_FEAT;   // 50000 nodes
    const int E = in_sizes[1];            // 200000 edges

    // workspace: qUV u8 [M][2048] | scales f32 [M][32] | xb bf16 [M][512] | w1t bf16 [2048][512]
    char* ws = (char*)d_ws;
    unsigned char*  qUV    = (unsigned char*)ws;
    float*          scales = (float*)(ws + (size_t)M * NCOL);
    unsigned short* xb     = (unsigned short*)(ws + (size_t)M * NCOL + (size_t)M * NCHUNK * 4);
    unsigned short* w1t    = (unsigned short*)(ws + (size_t)M * NCOL + (size_t)M * NCHUNK * 4
                                                  + (size_t)M * D_FEAT * 2);

    const int nx = M * D_FEAT;
    cast_x_kernel<<<(nx / 8 + 255) / 256, 256, 0, stream>>>(x, xb, nx);
    transpose_w1_kernel<<<dim3(32, 16, 2), dim3(32, 8), 0, stream>>>(W1, w1t);
    const int MB = (M + BM - 1) / BM;
    gemm_uv_kernel<<<MB * NB2, 512, 0, stream>>>(xb, w1t, b1, qUV, scales, M, MB);
    edge_score_kernel<<<(E + 7) / 8, 256, 0, stream>>>(qUV, scales, src, dst, W2, b2, out, E);
}